// Round 2
// baseline (4688.995 us; speedup 1.0000x reference)
//
#include <hip/hip_runtime.h>
#include <hip/hip_bf16.h>

#define N_NODES 20000
#define E_EDGES 320000
#define CIN 128
#define HDIM 128
#define EDGE_DIM 16
#define SDIM 3
#define KS 3
#define KK 27           // 3^3 kernel weight matrices
#define S_TAPS 8        // 2^3 spline taps per edge
#define MLP_HID 6

// ---------------------------------------------------------------------------
// Detect whether edge_index is stored as int64 (odd 32-bit words are the high
// halves -> all zero for values < 2^31) or int32. flag=1 => int32 layout.
// ---------------------------------------------------------------------------
__global__ void detect_kernel(const unsigned int* __restrict__ e, int* __restrict__ flag) {
    __shared__ int s_nz;
    if (threadIdx.x == 0) s_nz = 0;
    __syncthreads();
    unsigned int v = e[threadIdx.x * 2 + 1];   // odd 32-bit word
    if (v != 0) atomicAdd(&s_nz, 1);
    __syncthreads();
    if (threadIdx.x == 0) *flag = (s_nz > 0) ? 1 : 0;
}

__global__ void decode_edges(const void* __restrict__ eraw, const int* __restrict__ flag,
                             int* __restrict__ e32, int n) {
    int i = blockIdx.x * blockDim.x + threadIdx.x;
    if (i >= n) return;
    if (*flag) e32[i] = ((const int*)eraw)[i];
    else       e32[i] = (int)(((const long long*)eraw)[i]);
}

// ---------------------------------------------------------------------------
// Edge MLP (16->6 relu ->3 sigmoid) + degree-1 open B-spline basis.
// ---------------------------------------------------------------------------
__global__ void edge_basis(const float* __restrict__ ea,
                           const float* __restrict__ Wp1, const float* __restrict__ bp1,
                           const float* __restrict__ Wp2, const float* __restrict__ bp2,
                           float* __restrict__ bw, int* __restrict__ bidx) {
    __shared__ float sW1[EDGE_DIM * MLP_HID];
    __shared__ float sb1[MLP_HID];
    __shared__ float sW2[MLP_HID * SDIM];
    __shared__ float sb2[SDIM];
    int t = threadIdx.x;
    if (t < EDGE_DIM * MLP_HID) sW1[t] = Wp1[t];
    if (t < MLP_HID)            sb1[t] = bp1[t];
    if (t < MLP_HID * SDIM)     sW2[t] = Wp2[t];
    if (t < SDIM)               sb2[t] = bp2[t];
    __syncthreads();
    int e = blockIdx.x * blockDim.x + t;
    if (e >= E_EDGES) return;

    float a[EDGE_DIM];
#pragma unroll
    for (int i = 0; i < EDGE_DIM; i++) a[i] = ea[(long)e * EDGE_DIM + i];

    float hid[MLP_HID];
#pragma unroll
    for (int j = 0; j < MLP_HID; j++) {
        float s = sb1[j];
#pragma unroll
        for (int i = 0; i < EDGE_DIM; i++) s += a[i] * sW1[i * MLP_HID + j];
        hid[j] = fmaxf(s, 0.f);
    }

    float lo[SDIM], fr[SDIM];
#pragma unroll
    for (int d = 0; d < SDIM; d++) {
        float s = sb2[d];
#pragma unroll
        for (int j = 0; j < MLP_HID; j++) s += hid[j] * sW2[j * SDIM + d];
        float u = 1.f / (1.f + expf(-s));         // sigmoid
        float v = u * (float)(KS - 1);
        float l = floorf(v);
        l = fminf(fmaxf(l, 0.f), (float)(KS - 2));
        lo[d] = l;
        fr[d] = v - l;
    }

#pragma unroll
    for (int s = 0; s < S_TAPS; s++) {
        float w = 1.f;
        int idx = 0, stride = 1;
#pragma unroll
        for (int d = 0; d < SDIM; d++) {
            int bit = (s >> d) & 1;
            w *= bit ? fr[d] : (1.f - fr[d]);
            idx += ((int)lo[d] + bit) * stride;
            stride *= KS;
        }
        bw[(long)e * S_TAPS + s] = w;
        bidx[(long)e * S_TAPS + s] = idx;
    }
}

// ---------------------------------------------------------------------------
__global__ void zero_kernel(float4* __restrict__ p, long n4) {
    long i = (long)blockIdx.x * blockDim.x + threadIdx.x;
    long stride = (long)gridDim.x * blockDim.x;
    for (; i < n4; i += stride) p[i] = make_float4(0.f, 0.f, 0.f, 0.f);
}

// ---------------------------------------------------------------------------
// Scatter: T[((dst-n_lo)*27 + bidx[e,s]) * 128 + c] += bw[e,s] * xin[src, c]
// for dst in [n_lo, n_hi). One thread per (edge, channel); 8 atomics.
// ---------------------------------------------------------------------------
__global__ __launch_bounds__(256) void scatter_kernel(
    const float* __restrict__ xin,
    const int* __restrict__ src, const int* __restrict__ dst,
    const float* __restrict__ bw, const int* __restrict__ bidx,
    float* __restrict__ T, int n_lo, int n_hi)
{
    long gid = (long)blockIdx.x * blockDim.x + threadIdx.x;
    int c = (int)(gid & (CIN - 1));
    int e = (int)(gid >> 7);
    if (e >= E_EDGES) return;
    int d0 = dst[e];
    if (d0 < n_lo || d0 >= n_hi) return;
    int s0 = src[e];
    float val = xin[(long)s0 * CIN + c];
    long base = (long)(d0 - n_lo) * KK * CIN + c;
#pragma unroll
    for (int s = 0; s < S_TAPS; s++) {
        float w = bw[(long)e * S_TAPS + s];
        int k = bidx[(long)e * S_TAPS + s];
        atomicAdd(&T[base + (long)k * CIN], w * val);
    }
}

// ---------------------------------------------------------------------------
// Fused GEMM over node range [n_lo, n_lo + grid*BM):
//   out[n,o] = sum_kk T[n-n_lo,kk]*Wflat[kk,o] + sum_i xin[n,i]*Wr[i,o] + b[o]
// ---------------------------------------------------------------------------
#define BM 32
#define BN 128
#define BK 16

__global__ __launch_bounds__(256) void gemm_fused(
    const float* __restrict__ T, const float* __restrict__ Wflat,
    const float* __restrict__ xin, const float* __restrict__ Wr,
    const float* __restrict__ bias, float* __restrict__ out,
    int do_relu, int n_lo)
{
    __shared__ float As[BK][BM + 4];
    __shared__ float Bs[BK][BN];

    const int KT = (KK * CIN) / BK;    // 216 tiles from T/Wflat
    const int KR = CIN / BK;           // 8 tiles from xin/Wr

    int m0 = n_lo + blockIdx.x * BM;
    int tid = threadIdx.x;
    int tx = tid & 31;
    int ty = tid >> 5;

    int ar = tid >> 3;                 // 0..31
    int ac = (tid & 7) * 2;            // 0..14 step 2
    int br = tid >> 4;                 // 0..15
    int bc = (tid & 15) * 8;           // 0..120

    float acc[4][4] = {};

    for (int t = 0; t < KT + KR; t++) {
        long grow = (long)(m0 + ar);
        float a0 = 0.f, a1 = 0.f;
        if (grow < N_NODES) {
            const float* p = (t < KT)
                ? (T   + (grow - n_lo) * (long)(KK * CIN) + t * BK + ac)
                : (xin + grow * (long)CIN + (t - KT) * BK + ac);
            a0 = p[0]; a1 = p[1];
        }
        const float* bp = (t < KT)
            ? (Wflat + (long)(t * BK + br) * BN + bc)
            : (Wr    + (long)((t - KT) * BK + br) * BN + bc);
        float4 b0 = *(const float4*)(bp);
        float4 b1 = *(const float4*)(bp + 4);

        __syncthreads();
        As[ac][ar] = a0;
        As[ac + 1][ar] = a1;
        *(float4*)&Bs[br][bc] = b0;
        *(float4*)&Bs[br][bc + 4] = b1;
        __syncthreads();

#pragma unroll
        for (int k = 0; k < BK; k++) {
            float4 av = *(const float4*)&As[k][ty * 4];
            float4 bv = *(const float4*)&Bs[k][tx * 4];
            float avf[4] = {av.x, av.y, av.z, av.w};
            float bvf[4] = {bv.x, bv.y, bv.z, bv.w};
#pragma unroll
            for (int i = 0; i < 4; i++)
#pragma unroll
                for (int j = 0; j < 4; j++)
                    acc[i][j] += avf[i] * bvf[j];
        }
    }

#pragma unroll
    for (int i = 0; i < 4; i++) {
        long r = (long)m0 + ty * 4 + i;
        if (r >= N_NODES) continue;
#pragma unroll
        for (int j = 0; j < 4; j++) {
            int cI = tx * 4 + j;
            float v = acc[i][j] + bias[cI];
            if (do_relu) v = fmaxf(v, 0.f);
            out[r * HDIM + cI] = v;
        }
    }
}

// ---------------------------------------------------------------------------
extern "C" void kernel_launch(void* const* d_in, const int* in_sizes, int n_in,
                              void* d_out, int out_size, void* d_ws, size_t ws_size,
                              hipStream_t stream) {
    const float* x   = (const float*)d_in[0];
    const void*  eix = d_in[1];
    const float* ea  = (const float*)d_in[2];
    const float* Wp1 = (const float*)d_in[3];
    const float* bp1 = (const float*)d_in[4];
    const float* Wp2 = (const float*)d_in[5];
    const float* bp2 = (const float*)d_in[6];
    const float* W[3]  = {(const float*)d_in[7],  (const float*)d_in[10], (const float*)d_in[13]};
    const float* Wr[3] = {(const float*)d_in[8],  (const float*)d_in[11], (const float*)d_in[14]};
    const float* b[3]  = {(const float*)d_in[9],  (const float*)d_in[12], (const float*)d_in[15]};
    float* out = (float*)d_out;

    char* ws = (char*)d_ws;
    size_t off = 0;
    auto walloc = [&](size_t bytes) -> void* {
        void* p = ws + off;
        off = (off + bytes + 255) & ~(size_t)255;
        return p;
    };
    int*   flag = (int*)  walloc(sizeof(int));
    int*   e32  = (int*)  walloc(sizeof(int) * 2 * E_EDGES);
    float* bw   = (float*)walloc(sizeof(float) * E_EDGES * S_TAPS);
    int*   bidx = (int*)  walloc(sizeof(int) * E_EDGES * S_TAPS);
    float* h0   = (float*)walloc(sizeof(float) * (size_t)N_NODES * HDIM);
    float* h1   = (float*)walloc(sizeof(float) * (size_t)N_NODES * HDIM);
    // Remaining workspace goes to the per-(node,kernel) accumulator T.
    // Chunk the node range so T fits whatever ws_size the harness gave us.
    size_t avail = (ws_size > off) ? (ws_size - off) : 0;
    const size_t bytes_per_node = (size_t)KK * CIN * sizeof(float);   // 13824
    long chunk_nodes = (long)(avail / bytes_per_node);
    if (chunk_nodes > N_NODES) chunk_nodes = N_NODES;
    chunk_nodes = (chunk_nodes / BM) * BM;
    if (chunk_nodes < BM) chunk_nodes = BM;   // last resort; needs ~485 KB
    float* T = (float*)walloc(bytes_per_node * (size_t)chunk_nodes);

    int* srcv = e32;
    int* dstv = e32 + E_EDGES;

    detect_kernel<<<1, 1024, 0, stream>>>((const unsigned int*)eix, flag);
    decode_edges<<<(2 * E_EDGES + 255) / 256, 256, 0, stream>>>(eix, flag, e32, 2 * E_EDGES);
    edge_basis<<<(E_EDGES + 255) / 256, 256, 0, stream>>>(ea, Wp1, bp1, Wp2, bp2, bw, bidx);

    const float* lin[3]  = {x, h0, h1};
    float*       lout[3] = {h0, h1, out};

    const int scatter_blocks = (int)(((long)E_EDGES * CIN + 255) / 256);  // 160000

    for (int l = 0; l < 3; l++) {
        for (long n_lo = 0; n_lo < N_NODES; n_lo += chunk_nodes) {
            long nodes_this = N_NODES - n_lo;
            if (nodes_this > chunk_nodes) nodes_this = chunk_nodes;
            long n4 = nodes_this * KK * CIN / 4;
            zero_kernel<<<4096, 256, 0, stream>>>((float4*)T, n4);
            scatter_kernel<<<scatter_blocks, 256, 0, stream>>>(
                lin[l], srcv, dstv, bw, bidx, T, (int)n_lo, (int)(n_lo + nodes_this));
            gemm_fused<<<(int)((nodes_this + BM - 1) / BM), 256, 0, stream>>>(
                T, W[l], lin[l], Wr[l], b[l], lout[l], (l < 2) ? 1 : 0, (int)n_lo);
        }
    }
}

// Round 3
// 1243.244 us; speedup vs baseline: 3.7716x; 3.7716x over previous
//
#include <hip/hip_runtime.h>
#include <hip/hip_bf16.h>

#define N_NODES 20000
#define E_EDGES 320000
#define CIN 128
#define HDIM 128
#define EDGE_DIM 16
#define SDIM 3
#define KS 3
#define KK 27           // 3^3 kernel weight matrices
#define NB 28           // 27 spline blocks + 1 root-weight block
#define ZLD (NB * 128)  // Z leading dim = 3584
#define S_TAPS 8
#define MLP_HID 6
#define MT_TOTAL (N_NODES / 16)   // 1250 m-tiles of 16 rows

typedef __attribute__((ext_vector_type(8))) short v8s;   // 8 bf16 (4 VGPRs)
typedef __attribute__((ext_vector_type(4))) float v4f;   // MFMA accumulator

static __device__ __forceinline__ short f2bf(float v) {
    unsigned u = __float_as_uint(v);
    unsigned r = (u + 0x7fffu + ((u >> 16) & 1u)) >> 16;   // RTNE
    return (short)r;
}
static __device__ __forceinline__ float bf2f(short s) {
    return __uint_as_float(((unsigned)(unsigned short)s) << 16);
}

// ---------------------------------------------------------------------------
// edge_index dtype detect + decode (int64 vs int32 storage)
// ---------------------------------------------------------------------------
__global__ void detect_kernel(const unsigned int* __restrict__ e, int* __restrict__ flag) {
    __shared__ int s_nz;
    if (threadIdx.x == 0) s_nz = 0;
    __syncthreads();
    unsigned int v = e[threadIdx.x * 2 + 1];
    if (v != 0) atomicAdd(&s_nz, 1);
    __syncthreads();
    if (threadIdx.x == 0) *flag = (s_nz > 0) ? 1 : 0;
}

__global__ void decode_edges(const void* __restrict__ eraw, const int* __restrict__ flag,
                             int* __restrict__ e32, int n) {
    int i = blockIdx.x * blockDim.x + threadIdx.x;
    if (i >= n) return;
    if (*flag) e32[i] = ((const int*)eraw)[i];
    else       e32[i] = (int)(((const long long*)eraw)[i]);
}

// ---------------------------------------------------------------------------
// Edge MLP (16->6 relu ->3 sigmoid) + degree-1 open B-spline basis.
// ---------------------------------------------------------------------------
__global__ void edge_basis(const float* __restrict__ ea,
                           const float* __restrict__ Wp1, const float* __restrict__ bp1,
                           const float* __restrict__ Wp2, const float* __restrict__ bp2,
                           float* __restrict__ bw, int* __restrict__ bidx) {
    __shared__ float sW1[EDGE_DIM * MLP_HID];
    __shared__ float sb1[MLP_HID];
    __shared__ float sW2[MLP_HID * SDIM];
    __shared__ float sb2[SDIM];
    int t = threadIdx.x;
    if (t < EDGE_DIM * MLP_HID) sW1[t] = Wp1[t];
    if (t < MLP_HID)            sb1[t] = bp1[t];
    if (t < MLP_HID * SDIM)     sW2[t] = Wp2[t];
    if (t < SDIM)               sb2[t] = bp2[t];
    __syncthreads();
    int e = blockIdx.x * blockDim.x + t;
    if (e >= E_EDGES) return;

    float a[EDGE_DIM];
#pragma unroll
    for (int i = 0; i < EDGE_DIM; i++) a[i] = ea[(long)e * EDGE_DIM + i];

    float hid[MLP_HID];
#pragma unroll
    for (int j = 0; j < MLP_HID; j++) {
        float s = sb1[j];
#pragma unroll
        for (int i = 0; i < EDGE_DIM; i++) s += a[i] * sW1[i * MLP_HID + j];
        hid[j] = fmaxf(s, 0.f);
    }

    float lo[SDIM], fr[SDIM];
#pragma unroll
    for (int d = 0; d < SDIM; d++) {
        float s = sb2[d];
#pragma unroll
        for (int j = 0; j < MLP_HID; j++) s += hid[j] * sW2[j * SDIM + d];
        float u = 1.f / (1.f + expf(-s));
        float v = u * (float)(KS - 1);
        float l = floorf(v);
        l = fminf(fmaxf(l, 0.f), (float)(KS - 2));
        lo[d] = l;
        fr[d] = v - l;
    }

#pragma unroll
    for (int s = 0; s < S_TAPS; s++) {
        float w = 1.f;
        int idx = 0, stride = 1;
#pragma unroll
        for (int d = 0; d < SDIM; d++) {
            int bit = (s >> d) & 1;
            w *= bit ? fr[d] : (1.f - fr[d]);
            idx += ((int)lo[d] + bit) * stride;
            stride *= KS;
        }
        bw[(long)e * S_TAPS + s] = w;
        bidx[(long)e * S_TAPS + s] = idx;
    }
}

// ---------------------------------------------------------------------------
// CSR build (dst-sorted edge permutation) — built once, reused for 3 layers
// ---------------------------------------------------------------------------
__global__ void zero_int(int* __restrict__ p, int n) {
    int i = blockIdx.x * blockDim.x + threadIdx.x;
    if (i < n) p[i] = 0;
}

__global__ void hist_kernel(const int* __restrict__ dst, int* __restrict__ hist) {
    int e = blockIdx.x * blockDim.x + threadIdx.x;
    if (e < E_EDGES) atomicAdd(&hist[dst[e]], 1);
}

__global__ void scan_kernel(const int* __restrict__ hist, int* __restrict__ rowptr) {
    __shared__ int part[256];
    int t = threadIdx.x;
    const int per = (N_NODES + 255) / 256;   // 79
    int base = t * per;
    int s = 0;
    for (int i = 0; i < per; i++) {
        int idx = base + i;
        if (idx < N_NODES) s += hist[idx];
    }
    part[t] = s;
    __syncthreads();
    for (int off = 1; off < 256; off <<= 1) {
        int v = (t >= off) ? part[t - off] : 0;
        __syncthreads();
        part[t] += v;
        __syncthreads();
    }
    int run = (t == 0) ? 0 : part[t - 1];
    for (int i = 0; i < per; i++) {
        int idx = base + i;
        if (idx < N_NODES) { rowptr[idx] = run; run += hist[idx]; }
    }
    if (t == 255) rowptr[N_NODES] = run;
}

__global__ void perm_kernel(const int* __restrict__ dst, const int* __restrict__ rowptr,
                            int* __restrict__ cursor, int* __restrict__ eperm) {
    int e = blockIdx.x * blockDim.x + threadIdx.x;
    if (e >= E_EDGES) return;
    int d = dst[e];
    int pos = rowptr[d] + atomicAdd(&cursor[d], 1);
    eperm[pos] = e;
}

// ---------------------------------------------------------------------------
// Convert activations -> bf16 hi/lo in MFMA A-fragment layout.
// Apack[mtile][kstep][lane][8]; element = A[mtile*16 + (lane&15)]
//                                        [kstep*32 + (lane>>4)*8 + j]
// ---------------------------------------------------------------------------
__global__ void convA_kernel(const float* __restrict__ A, short* __restrict__ hi,
                             short* __restrict__ lo, int do_relu) {
    int gid = blockIdx.x * blockDim.x + threadIdx.x;
    if (gid >= MT_TOTAL * 4 * 64) return;
    int lane = gid & 63;
    int ks = (gid >> 6) & 3;
    int mt = gid >> 8;
    int row = mt * 16 + (lane & 15);
    int col = ks * 32 + ((lane >> 4) & 3) * 8;
    const float* p = A + (long)row * CIN + col;
    long off = ((long)(mt * 4 + ks) * 64 + lane) * 8;
#pragma unroll
    for (int j = 0; j < 8; j++) {
        float v = p[j];
        if (do_relu) v = fmaxf(v, 0.f);
        short h = f2bf(v);
        float r = v - bf2f(h);
        hi[off + j] = h;
        lo[off + j] = f2bf(r);
    }
}

// ---------------------------------------------------------------------------
// Pack [W (27 blocks) | Wr] -> bf16 hi/lo in MFMA B-fragment layout.
// Wpack[kb][kstep][ntile][lane][8]; element = B[kstep*32+(lane>>4)*8+j]
//                                             [ntile*16 + (lane&15)]  of block kb
// ---------------------------------------------------------------------------
__global__ void packW_kernel(const float* __restrict__ W, const float* __restrict__ Wr,
                             short* __restrict__ hi, short* __restrict__ lo) {
    int gid = blockIdx.x * blockDim.x + threadIdx.x;
    if (gid >= NB * 4 * 8 * 64) return;
    int lane = gid & 63;
    int nt = (gid >> 6) & 7;
    int ks = (gid >> 9) & 3;
    int kb = gid >> 11;
    int i0 = ks * 32 + ((lane >> 4) & 3) * 8;
    int o = nt * 16 + (lane & 15);
    const float* src = (kb < KK) ? (W + (long)kb * 16384 + (long)i0 * 128 + o)
                                 : (Wr + (long)i0 * 128 + o);
    long off = ((long)((kb * 4 + ks) * 8 + nt) * 64 + lane) * 8;
#pragma unroll
    for (int j = 0; j < 8; j++) {
        float v = src[(long)j * 128];
        short h = f2bf(v);
        float r = v - bf2f(h);
        hi[off + j] = h;
        lo[off + j] = f2bf(r);
    }
}

// ---------------------------------------------------------------------------
// MFMA GEMM: Z[row-row_lo, kb*128+o] = sum_i A[row,i] * B[kb][i][o]
// Split-bf16 3-pass (AhiBhi + AloBhi + AhiBlo) ~= fp32.
// Block = 256 thr = 4 waves; each wave: 2 m-tiles x 8 n-tiles (32x128 of C).
// grid.x covers m-tiles of the chunk, grid.y = 28 (kb).
// No LDS, no barriers: frags load straight from packed global (L2-hot).
// ---------------------------------------------------------------------------
__global__ __launch_bounds__(256) void gemm_kernel(
    const short* __restrict__ Ah, const short* __restrict__ Al,
    const short* __restrict__ Wh, const short* __restrict__ Wl,
    float* __restrict__ Z, int mtile_lo, int mtile_hi, int row_lo, int row_hi)
{
    int wave = threadIdx.x >> 6;
    int lane = threadIdx.x & 63;
    int mt0 = mtile_lo + blockIdx.x * 8 + wave * 2;
    if (mt0 >= mtile_hi) return;
    int mt1 = (mt0 + 1 < mtile_hi) ? (mt0 + 1) : mt0;
    int kb = blockIdx.y;

    v4f acc[2][8];
#pragma unroll
    for (int m = 0; m < 2; m++)
#pragma unroll
        for (int n = 0; n < 8; n++) acc[m][n] = (v4f){0.f, 0.f, 0.f, 0.f};

#pragma unroll
    for (int ks = 0; ks < 4; ks++) {
        long a0 = ((long)(mt0 * 4 + ks) * 64 + lane) * 8;
        long a1 = ((long)(mt1 * 4 + ks) * 64 + lane) * 8;
        v8s ah0 = *(const v8s*)(Ah + a0);
        v8s al0 = *(const v8s*)(Al + a0);
        v8s ah1 = *(const v8s*)(Ah + a1);
        v8s al1 = *(const v8s*)(Al + a1);
#pragma unroll
        for (int nt = 0; nt < 8; nt++) {
            long boff = ((long)((kb * 4 + ks) * 8 + nt) * 64 + lane) * 8;
            v8s bh = *(const v8s*)(Wh + boff);
            v8s bl = *(const v8s*)(Wl + boff);
            acc[0][nt] = __builtin_amdgcn_mfma_f32_16x16x32_bf16(ah0, bh, acc[0][nt], 0, 0, 0);
            acc[0][nt] = __builtin_amdgcn_mfma_f32_16x16x32_bf16(al0, bh, acc[0][nt], 0, 0, 0);
            acc[0][nt] = __builtin_amdgcn_mfma_f32_16x16x32_bf16(ah0, bl, acc[0][nt], 0, 0, 0);
            acc[1][nt] = __builtin_amdgcn_mfma_f32_16x16x32_bf16(ah1, bh, acc[1][nt], 0, 0, 0);
            acc[1][nt] = __builtin_amdgcn_mfma_f32_16x16x32_bf16(al1, bh, acc[1][nt], 0, 0, 0);
            acc[1][nt] = __builtin_amdgcn_mfma_f32_16x16x32_bf16(ah1, bl, acc[1][nt], 0, 0, 0);
        }
    }

    // C/D layout: col = lane&15, row-in-tile = (lane>>4)*4 + reg
#pragma unroll
    for (int m = 0; m < 2; m++) {
        int mtg = mt0 + m;
        if (mtg >= mtile_hi) break;
#pragma unroll
        for (int nt = 0; nt < 8; nt++) {
            int col = kb * 128 + nt * 16 + (lane & 15);
#pragma unroll
            for (int r = 0; r < 4; r++) {
                int row = mtg * 16 + ((lane >> 4) & 3) * 4 + r;
                if (row >= row_hi) continue;
                Z[(size_t)(row - row_lo) * ZLD + col] = acc[m][nt][r];
            }
        }
    }
}

// ---------------------------------------------------------------------------
// Gather: one wave per dst node. For each incident edge with src in chunk:
// acc += sum_s bw[e,s] * Z[src, bidx[e,s]*128 + c].  Plus root (Z block 27)
// + bias in the chunk owning this node. RMW of own out row across chunks —
// no atomics (wave exclusively owns the row; chunks are sequential launches).
// ---------------------------------------------------------------------------
__global__ __launch_bounds__(256) void gather_kernel(
    const float* __restrict__ Z, const int* __restrict__ rowptr,
    const int* __restrict__ eperm, const int* __restrict__ src,
    const float* __restrict__ bw, const int* __restrict__ bidx,
    const float* __restrict__ bias, float* __restrict__ outp,
    int lo, int hi, int first)
{
    int wave = threadIdx.x >> 6;
    int lane = threadIdx.x & 63;
    int n = blockIdx.x * 4 + wave;
    int c0 = lane * 2;
    unsigned span = (unsigned)(hi - lo);

    float ax = 0.f, ay = 0.f, bx = 0.f, by = 0.f;
    int jb = rowptr[n], je = rowptr[n + 1];
    for (int j = jb; j < je; j++) {
        int e = eperm[j];
        int s = src[e];
        if ((unsigned)(s - lo) >= span) continue;
        const float4* w4 = (const float4*)(bw + (long)e * 8);
        const int4*   k4 = (const int4*)(bidx + (long)e * 8);
        float4 w0 = w4[0], w1 = w4[1];
        int4   k0 = k4[0], k1 = k4[1];
        const float* zb = Z + (size_t)(s - lo) * ZLD + c0;
        float2 z;
        z = *(const float2*)(zb + k0.x * 128); ax += w0.x * z.x; ay += w0.x * z.y;
        z = *(const float2*)(zb + k0.y * 128); bx += w0.y * z.x; by += w0.y * z.y;
        z = *(const float2*)(zb + k0.z * 128); ax += w0.z * z.x; ay += w0.z * z.y;
        z = *(const float2*)(zb + k0.w * 128); bx += w0.w * z.x; by += w0.w * z.y;
        z = *(const float2*)(zb + k1.x * 128); ax += w1.x * z.x; ay += w1.x * z.y;
        z = *(const float2*)(zb + k1.y * 128); bx += w1.y * z.x; by += w1.y * z.y;
        z = *(const float2*)(zb + k1.z * 128); ax += w1.z * z.x; ay += w1.z * z.y;
        z = *(const float2*)(zb + k1.w * 128); bx += w1.w * z.x; by += w1.w * z.y;
    }
    float rx = ax + bx, ry = ay + by;
    if ((unsigned)(n - lo) < span) {
        const float* zr = Z + (size_t)(n - lo) * ZLD + KK * 128 + c0;
        rx += zr[0] + bias[c0];
        ry += zr[1] + bias[c0 + 1];
    }
    float* op = outp + (size_t)n * HDIM + c0;
    if (!first) { rx += op[0]; ry += op[1]; }
    op[0] = rx; op[1] = ry;
}

// ---------------------------------------------------------------------------
extern "C" void kernel_launch(void* const* d_in, const int* in_sizes, int n_in,
                              void* d_out, int out_size, void* d_ws, size_t ws_size,
                              hipStream_t stream) {
    const float* x   = (const float*)d_in[0];
    const void*  eix = d_in[1];
    const float* ea  = (const float*)d_in[2];
    const float* Wp1 = (const float*)d_in[3];
    const float* bp1 = (const float*)d_in[4];
    const float* Wp2 = (const float*)d_in[5];
    const float* bp2 = (const float*)d_in[6];
    const float* W[3]  = {(const float*)d_in[7],  (const float*)d_in[10], (const float*)d_in[13]};
    const float* Wr[3] = {(const float*)d_in[8],  (const float*)d_in[11], (const float*)d_in[14]};
    const float* b[3]  = {(const float*)d_in[9],  (const float*)d_in[12], (const float*)d_in[15]};
    float* out = (float*)d_out;

    char* ws = (char*)d_ws;
    size_t off = 0;
    auto walloc = [&](size_t bytes) -> void* {
        void* p = ws + off;
        off = (off + bytes + 255) & ~(size_t)255;
        return p;
    };
    int*   flag   = (int*)  walloc(sizeof(int));
    int*   e32    = (int*)  walloc(sizeof(int) * 2 * E_EDGES);
    float* bw     = (float*)walloc(sizeof(float) * E_EDGES * S_TAPS);
    int*   bidx   = (int*)  walloc(sizeof(int) * E_EDGES * S_TAPS);
    float* h0     = (float*)walloc(sizeof(float) * (size_t)N_NODES * HDIM);
    float* h1     = (float*)walloc(sizeof(float) * (size_t)N_NODES * HDIM);
    short* Ah     = (short*)walloc(sizeof(short) * (size_t)N_NODES * CIN);
    short* Al     = (short*)walloc(sizeof(short) * (size_t)N_NODES * CIN);
    short* Wh     = (short*)walloc(sizeof(short) * (size_t)NB * 128 * 128);
    short* Wl     = (short*)walloc(sizeof(short) * (size_t)NB * 128 * 128);
    int*   hist   = (int*)  walloc(sizeof(int) * N_NODES);
    int*   cursor = (int*)  walloc(sizeof(int) * N_NODES);
    int*   rowptr = (int*)  walloc(sizeof(int) * (N_NODES + 1));
    int*   eperm  = (int*)  walloc(sizeof(int) * E_EDGES);

    size_t avail = (ws_size > off) ? (ws_size - off) : 0;
    const size_t bytes_per_row = (size_t)ZLD * sizeof(float);   // 14336
    long chunk_rows = (long)(avail / bytes_per_row);
    if (chunk_rows > N_NODES) chunk_rows = N_NODES;
    chunk_rows = (chunk_rows / 128) * 128;
    if (chunk_rows < 128) chunk_rows = 128;
    float* Z = (float*)walloc(bytes_per_row * (size_t)chunk_rows);

    int* srcv = e32;
    int* dstv = e32 + E_EDGES;

    detect_kernel<<<1, 1024, 0, stream>>>((const unsigned int*)eix, flag);
    decode_edges<<<(2 * E_EDGES + 255) / 256, 256, 0, stream>>>(eix, flag, e32, 2 * E_EDGES);
    edge_basis<<<(E_EDGES + 255) / 256, 256, 0, stream>>>(ea, Wp1, bp1, Wp2, bp2, bw, bidx);

    // CSR by dst (once; reused across all 3 layers)
    zero_int<<<(2 * N_NODES + 255) / 256, 256, 0, stream>>>(hist, 2 * N_NODES); // hist+cursor adjacent? no — zero separately
    zero_int<<<(N_NODES + 255) / 256, 256, 0, stream>>>(cursor, N_NODES);
    hist_kernel<<<(E_EDGES + 255) / 256, 256, 0, stream>>>(dstv, hist);
    scan_kernel<<<1, 256, 0, stream>>>(hist, rowptr);
    perm_kernel<<<(E_EDGES + 255) / 256, 256, 0, stream>>>(dstv, rowptr, cursor, eperm);

    const float* lin[3]  = {x, h0, h1};
    float*       lout[3] = {h0, h1, out};

    for (int l = 0; l < 3; l++) {
        convA_kernel<<<(MT_TOTAL * 4 * 64 + 255) / 256, 256, 0, stream>>>(
            lin[l], Ah, Al, (l > 0) ? 1 : 0);
        packW_kernel<<<(NB * 4 * 8 * 64 + 255) / 256, 256, 0, stream>>>(
            W[l], Wr[l], Wh, Wl);
        int chunk_id = 0;
        for (long lo = 0; lo < N_NODES; lo += chunk_rows, chunk_id++) {
            long hi = lo + chunk_rows;
            if (hi > N_NODES) hi = N_NODES;
            int mtile_lo = (int)(lo / 16);
            int mtile_hi = (int)(hi / 16);   // hi is multiple of 16 (128 | chunk, 16 | 20000)
            int gx = (mtile_hi - mtile_lo + 7) / 8;
            dim3 grid(gx, NB);
            gemm_kernel<<<grid, 256, 0, stream>>>(Ah, Al, Wh, Wl, Z,
                                                  mtile_lo, mtile_hi, (int)lo, (int)hi);
            gather_kernel<<<N_NODES / 4, 256, 0, stream>>>(
                Z, rowptr, eperm, srcv, bw, bidx, b[l], lout[l],
                (int)lo, (int)hi, (chunk_id == 0) ? 1 : 0);
        }
    }
}

// Round 4
// 998.576 us; speedup vs baseline: 4.6957x; 1.2450x over previous
//
#include <hip/hip_runtime.h>
#include <hip/hip_bf16.h>

#define N_NODES 20000
#define E_EDGES 320000
#define CIN 128
#define HDIM 128
#define EDGE_DIM 16
#define SDIM 3
#define KS 3
#define KK 27           // 3^3 kernel weight matrices
#define NB 28           // 27 spline blocks + 1 root-weight block
#define ZLD (NB * 128)  // Z leading dim = 3584 elements (bf16)
#define S_TAPS 8
#define MLP_HID 6
#define MT_TOTAL (N_NODES / 16)   // 1250 m-tiles of 16 rows

typedef __attribute__((ext_vector_type(8))) short v8s;   // 8 bf16 (4 VGPRs)
typedef __attribute__((ext_vector_type(4))) float v4f;   // MFMA accumulator
typedef unsigned short ush;

static __device__ __forceinline__ short f2bf(float v) {
    unsigned u = __float_as_uint(v);
    unsigned r = (u + 0x7fffu + ((u >> 16) & 1u)) >> 16;   // RTNE
    return (short)r;
}
static __device__ __forceinline__ float bf2f(unsigned s) {
    return __uint_as_float((s & 0xffffu) << 16);
}

// ---------------------------------------------------------------------------
// edge_index dtype detect + decode (int64 vs int32 storage)
// ---------------------------------------------------------------------------
__global__ void detect_kernel(const unsigned int* __restrict__ e, int* __restrict__ flag) {
    __shared__ int s_nz;
    if (threadIdx.x == 0) s_nz = 0;
    __syncthreads();
    unsigned int v = e[threadIdx.x * 2 + 1];
    if (v != 0) atomicAdd(&s_nz, 1);
    __syncthreads();
    if (threadIdx.x == 0) *flag = (s_nz > 0) ? 1 : 0;
}

__global__ void decode_edges(const void* __restrict__ eraw, const int* __restrict__ flag,
                             int* __restrict__ e32, int n) {
    int i = blockIdx.x * blockDim.x + threadIdx.x;
    if (i >= n) return;
    if (*flag) e32[i] = ((const int*)eraw)[i];
    else       e32[i] = (int)(((const long long*)eraw)[i]);
}

// ---------------------------------------------------------------------------
// Edge MLP (16->6 relu ->3 sigmoid) + degree-1 open B-spline basis.
// ---------------------------------------------------------------------------
__global__ void edge_basis(const float* __restrict__ ea,
                           const float* __restrict__ Wp1, const float* __restrict__ bp1,
                           const float* __restrict__ Wp2, const float* __restrict__ bp2,
                           float* __restrict__ bw, int* __restrict__ bidx) {
    __shared__ float sW1[EDGE_DIM * MLP_HID];
    __shared__ float sb1[MLP_HID];
    __shared__ float sW2[MLP_HID * SDIM];
    __shared__ float sb2[SDIM];
    int t = threadIdx.x;
    if (t < EDGE_DIM * MLP_HID) sW1[t] = Wp1[t];
    if (t < MLP_HID)            sb1[t] = bp1[t];
    if (t < MLP_HID * SDIM)     sW2[t] = Wp2[t];
    if (t < SDIM)               sb2[t] = bp2[t];
    __syncthreads();
    int e = blockIdx.x * blockDim.x + t;
    if (e >= E_EDGES) return;

    float a[EDGE_DIM];
#pragma unroll
    for (int i = 0; i < EDGE_DIM; i++) a[i] = ea[(long)e * EDGE_DIM + i];

    float hid[MLP_HID];
#pragma unroll
    for (int j = 0; j < MLP_HID; j++) {
        float s = sb1[j];
#pragma unroll
        for (int i = 0; i < EDGE_DIM; i++) s += a[i] * sW1[i * MLP_HID + j];
        hid[j] = fmaxf(s, 0.f);
    }

    float lo[SDIM], fr[SDIM];
#pragma unroll
    for (int d = 0; d < SDIM; d++) {
        float s = sb2[d];
#pragma unroll
        for (int j = 0; j < MLP_HID; j++) s += hid[j] * sW2[j * SDIM + d];
        float u = 1.f / (1.f + expf(-s));
        float v = u * (float)(KS - 1);
        float l = floorf(v);
        l = fminf(fmaxf(l, 0.f), (float)(KS - 2));
        lo[d] = l;
        fr[d] = v - l;
    }

#pragma unroll
    for (int s = 0; s < S_TAPS; s++) {
        float w = 1.f;
        int idx = 0, stride = 1;
#pragma unroll
        for (int d = 0; d < SDIM; d++) {
            int bit = (s >> d) & 1;
            w *= bit ? fr[d] : (1.f - fr[d]);
            idx += ((int)lo[d] + bit) * stride;
            stride *= KS;
        }
        bw[(long)e * S_TAPS + s] = w;
        bidx[(long)e * S_TAPS + s] = idx;
    }
}

// ---------------------------------------------------------------------------
// CSR build (dst-sorted edge permutation) — built once, reused for 3 layers
// ---------------------------------------------------------------------------
__global__ void zero_int(int* __restrict__ p, int n) {
    int i = blockIdx.x * blockDim.x + threadIdx.x;
    if (i < n) p[i] = 0;
}

__global__ void hist_kernel(const int* __restrict__ dst, int* __restrict__ hist) {
    int e = blockIdx.x * blockDim.x + threadIdx.x;
    if (e < E_EDGES) atomicAdd(&hist[dst[e]], 1);
}

__global__ void scan_kernel(const int* __restrict__ hist, int* __restrict__ rowptr) {
    __shared__ int part[256];
    int t = threadIdx.x;
    const int per = (N_NODES + 255) / 256;   // 79
    int base = t * per;
    int s = 0;
    for (int i = 0; i < per; i++) {
        int idx = base + i;
        if (idx < N_NODES) s += hist[idx];
    }
    part[t] = s;
    __syncthreads();
    for (int off = 1; off < 256; off <<= 1) {
        int v = (t >= off) ? part[t - off] : 0;
        __syncthreads();
        part[t] += v;
        __syncthreads();
    }
    int run = (t == 0) ? 0 : part[t - 1];
    for (int i = 0; i < per; i++) {
        int idx = base + i;
        if (idx < N_NODES) { rowptr[idx] = run; run += hist[idx]; }
    }
    if (t == 255) rowptr[N_NODES] = run;
}

__global__ void perm_kernel(const int* __restrict__ dst, const int* __restrict__ rowptr,
                            int* __restrict__ cursor, int* __restrict__ eperm) {
    int e = blockIdx.x * blockDim.x + threadIdx.x;
    if (e >= E_EDGES) return;
    int d = dst[e];
    int pos = rowptr[d] + atomicAdd(&cursor[d], 1);
    eperm[pos] = e;
}

// ---------------------------------------------------------------------------
// Convert activations -> bf16 hi/lo in MFMA A-fragment layout.
// ---------------------------------------------------------------------------
__global__ void convA_kernel(const float* __restrict__ A, short* __restrict__ hi,
                             short* __restrict__ lo, int do_relu) {
    int gid = blockIdx.x * blockDim.x + threadIdx.x;
    if (gid >= MT_TOTAL * 4 * 64) return;
    int lane = gid & 63;
    int ks = (gid >> 6) & 3;
    int mt = gid >> 8;
    int row = mt * 16 + (lane & 15);
    int col = ks * 32 + ((lane >> 4) & 3) * 8;
    const float* p = A + (long)row * CIN + col;
    long off = ((long)(mt * 4 + ks) * 64 + lane) * 8;
#pragma unroll
    for (int j = 0; j < 8; j++) {
        float v = p[j];
        if (do_relu) v = fmaxf(v, 0.f);
        short h = f2bf(v);
        float r = v - bf2f((unsigned short)h);
        hi[off + j] = h;
        lo[off + j] = f2bf(r);
    }
}

// ---------------------------------------------------------------------------
// Pack [W (27 blocks) | Wr] -> bf16 hi/lo in MFMA B-fragment layout.
// ---------------------------------------------------------------------------
__global__ void packW_kernel(const float* __restrict__ W, const float* __restrict__ Wr,
                             short* __restrict__ hi, short* __restrict__ lo) {
    int gid = blockIdx.x * blockDim.x + threadIdx.x;
    if (gid >= NB * 4 * 8 * 64) return;
    int lane = gid & 63;
    int nt = (gid >> 6) & 7;
    int ks = (gid >> 9) & 3;
    int kb = gid >> 11;
    int i0 = ks * 32 + ((lane >> 4) & 3) * 8;
    int o = nt * 16 + (lane & 15);
    const float* src = (kb < KK) ? (W + (long)kb * 16384 + (long)i0 * 128 + o)
                                 : (Wr + (long)i0 * 128 + o);
    long off = ((long)((kb * 4 + ks) * 8 + nt) * 64 + lane) * 8;
#pragma unroll
    for (int j = 0; j < 8; j++) {
        float v = src[(long)j * 128];
        short h = f2bf(v);
        float r = v - bf2f((unsigned short)h);
        hi[off + j] = h;
        lo[off + j] = f2bf(r);
    }
}

// ---------------------------------------------------------------------------
// MFMA GEMM: Z[row-row_lo, kb*128+o] = sum_i A[row,i]*B[kb][i][o]  (bf16 out)
// Split-bf16 3-pass (AhiBhi + AloBhi + AhiBlo) ~= fp32 inputs.
// ---------------------------------------------------------------------------
__global__ __launch_bounds__(256) void gemm_kernel(
    const short* __restrict__ Ah, const short* __restrict__ Al,
    const short* __restrict__ Wh, const short* __restrict__ Wl,
    ush* __restrict__ Z, int mtile_lo, int mtile_hi, int row_lo, int row_hi)
{
    int wave = threadIdx.x >> 6;
    int lane = threadIdx.x & 63;
    int mt0 = mtile_lo + blockIdx.x * 8 + wave * 2;
    if (mt0 >= mtile_hi) return;
    int mt1 = (mt0 + 1 < mtile_hi) ? (mt0 + 1) : mt0;
    int kb = blockIdx.y;

    v4f acc[2][8];
#pragma unroll
    for (int m = 0; m < 2; m++)
#pragma unroll
        for (int n = 0; n < 8; n++) acc[m][n] = (v4f){0.f, 0.f, 0.f, 0.f};

#pragma unroll
    for (int ks = 0; ks < 4; ks++) {
        long a0 = ((long)(mt0 * 4 + ks) * 64 + lane) * 8;
        long a1 = ((long)(mt1 * 4 + ks) * 64 + lane) * 8;
        v8s ah0 = *(const v8s*)(Ah + a0);
        v8s al0 = *(const v8s*)(Al + a0);
        v8s ah1 = *(const v8s*)(Ah + a1);
        v8s al1 = *(const v8s*)(Al + a1);
#pragma unroll
        for (int nt = 0; nt < 8; nt++) {
            long boff = ((long)((kb * 4 + ks) * 8 + nt) * 64 + lane) * 8;
            v8s bh = *(const v8s*)(Wh + boff);
            v8s bl = *(const v8s*)(Wl + boff);
            acc[0][nt] = __builtin_amdgcn_mfma_f32_16x16x32_bf16(ah0, bh, acc[0][nt], 0, 0, 0);
            acc[0][nt] = __builtin_amdgcn_mfma_f32_16x16x32_bf16(al0, bh, acc[0][nt], 0, 0, 0);
            acc[0][nt] = __builtin_amdgcn_mfma_f32_16x16x32_bf16(ah0, bl, acc[0][nt], 0, 0, 0);
            acc[1][nt] = __builtin_amdgcn_mfma_f32_16x16x32_bf16(ah1, bh, acc[1][nt], 0, 0, 0);
            acc[1][nt] = __builtin_amdgcn_mfma_f32_16x16x32_bf16(al1, bh, acc[1][nt], 0, 0, 0);
            acc[1][nt] = __builtin_amdgcn_mfma_f32_16x16x32_bf16(ah1, bl, acc[1][nt], 0, 0, 0);
        }
    }

    // C/D layout: col = lane&15, row-in-tile = (lane>>4)*4 + reg
#pragma unroll
    for (int m = 0; m < 2; m++) {
        int mtg = mt0 + m;
        if (mtg >= mtile_hi) break;
#pragma unroll
        for (int nt = 0; nt < 8; nt++) {
            int col = kb * 128 + nt * 16 + (lane & 15);
#pragma unroll
            for (int r = 0; r < 4; r++) {
                int row = mtg * 16 + ((lane >> 4) & 3) * 4 + r;
                if (row >= row_hi) continue;
                Z[(size_t)(row - row_lo) * ZLD + col] = (ush)f2bf(acc[m][nt][r]);
            }
        }
    }
}

// ---------------------------------------------------------------------------
// Gather: one wave per dst node; lane owns 2 channels. bf16 Z reads (256 B
// per tap per wave). RMW of own out row across chunks — no atomics.
// ---------------------------------------------------------------------------
__global__ __launch_bounds__(256) void gather_kernel(
    const ush* __restrict__ Z, const int* __restrict__ rowptr,
    const int* __restrict__ eperm, const int* __restrict__ src,
    const float* __restrict__ bw, const int* __restrict__ bidx,
    const float* __restrict__ bias, float* __restrict__ outp,
    int lo, int hi, int first)
{
    int wave = threadIdx.x >> 6;
    int lane = threadIdx.x & 63;
    int n = blockIdx.x * 4 + wave;
    int c0 = lane * 2;
    unsigned span = (unsigned)(hi - lo);

    float ax = 0.f, ay = 0.f, bx = 0.f, by = 0.f;
    int jb = rowptr[n], je = rowptr[n + 1];
    for (int j = jb; j < je; j++) {
        int e = eperm[j];
        int s = src[e];
        if ((unsigned)(s - lo) >= span) continue;
        const float4* w4 = (const float4*)(bw + (long)e * 8);
        const int4*   k4 = (const int4*)(bidx + (long)e * 8);
        float4 w0 = w4[0], w1 = w4[1];
        int4   k0 = k4[0], k1 = k4[1];
        const ush* zb = Z + (size_t)(s - lo) * ZLD + c0;
        ushort2 z;
        z = *(const ushort2*)(zb + k0.x * 128); ax += w0.x * bf2f(z.x); ay += w0.x * bf2f(z.y);
        z = *(const ushort2*)(zb + k0.y * 128); bx += w0.y * bf2f(z.x); by += w0.y * bf2f(z.y);
        z = *(const ushort2*)(zb + k0.z * 128); ax += w0.z * bf2f(z.x); ay += w0.z * bf2f(z.y);
        z = *(const ushort2*)(zb + k0.w * 128); bx += w0.w * bf2f(z.x); by += w0.w * bf2f(z.y);
        z = *(const ushort2*)(zb + k1.x * 128); ax += w1.x * bf2f(z.x); ay += w1.x * bf2f(z.y);
        z = *(const ushort2*)(zb + k1.y * 128); bx += w1.y * bf2f(z.x); by += w1.y * bf2f(z.y);
        z = *(const ushort2*)(zb + k1.z * 128); ax += w1.z * bf2f(z.x); ay += w1.z * bf2f(z.y);
        z = *(const ushort2*)(zb + k1.w * 128); bx += w1.w * bf2f(z.x); by += w1.w * bf2f(z.y);
    }
    float rx = ax + bx, ry = ay + by;
    if ((unsigned)(n - lo) < span) {
        const ush* zr = Z + (size_t)(n - lo) * ZLD + KK * 128 + c0;
        rx += bf2f(zr[0]) + bias[c0];
        ry += bf2f(zr[1]) + bias[c0 + 1];
    }
    float* op = outp + (size_t)n * HDIM + c0;
    if (!first) { rx += op[0]; ry += op[1]; }
    op[0] = rx; op[1] = ry;
}

// ---------------------------------------------------------------------------
extern "C" void kernel_launch(void* const* d_in, const int* in_sizes, int n_in,
                              void* d_out, int out_size, void* d_ws, size_t ws_size,
                              hipStream_t stream) {
    const float* x   = (const float*)d_in[0];
    const void*  eix = d_in[1];
    const float* ea  = (const float*)d_in[2];
    const float* Wp1 = (const float*)d_in[3];
    const float* bp1 = (const float*)d_in[4];
    const float* Wp2 = (const float*)d_in[5];
    const float* bp2 = (const float*)d_in[6];
    const float* W[3]  = {(const float*)d_in[7],  (const float*)d_in[10], (const float*)d_in[13]};
    const float* Wr[3] = {(const float*)d_in[8],  (const float*)d_in[11], (const float*)d_in[14]};
    const float* b[3]  = {(const float*)d_in[9],  (const float*)d_in[12], (const float*)d_in[15]};
    float* out = (float*)d_out;

    char* ws = (char*)d_ws;
    size_t off = 0;
    auto walloc = [&](size_t bytes) -> void* {
        void* p = ws + off;
        off = (off + bytes + 255) & ~(size_t)255;
        return p;
    };
    int*   flag   = (int*)  walloc(sizeof(int));
    int*   e32    = (int*)  walloc(sizeof(int) * 2 * E_EDGES);
    float* bw     = (float*)walloc(sizeof(float) * E_EDGES * S_TAPS);
    int*   bidx   = (int*)  walloc(sizeof(int) * E_EDGES * S_TAPS);
    float* h0     = (float*)walloc(sizeof(float) * (size_t)N_NODES * HDIM);
    float* h1     = (float*)walloc(sizeof(float) * (size_t)N_NODES * HDIM);
    short* Ah     = (short*)walloc(sizeof(short) * (size_t)N_NODES * CIN);
    short* Al     = (short*)walloc(sizeof(short) * (size_t)N_NODES * CIN);
    short* Wh     = (short*)walloc(sizeof(short) * (size_t)NB * 128 * 128);
    short* Wl     = (short*)walloc(sizeof(short) * (size_t)NB * 128 * 128);
    int*   hist   = (int*)  walloc(sizeof(int) * N_NODES);
    int*   cursor = (int*)  walloc(sizeof(int) * N_NODES);
    int*   rowptr = (int*)  walloc(sizeof(int) * (N_NODES + 1));
    int*   eperm  = (int*)  walloc(sizeof(int) * E_EDGES);

    size_t avail = (ws_size > off) ? (ws_size - off) : 0;
    const size_t bytes_per_row = (size_t)ZLD * sizeof(ush);   // 7168
    long chunk_rows = (long)(avail / bytes_per_row);
    if (chunk_rows > N_NODES) chunk_rows = N_NODES;
    chunk_rows = (chunk_rows / 128) * 128;
    if (chunk_rows < 128) chunk_rows = 128;
    ush* Z = (ush*)walloc(bytes_per_row * (size_t)chunk_rows);

    int* srcv = e32;
    int* dstv = e32 + E_EDGES;

    detect_kernel<<<1, 1024, 0, stream>>>((const unsigned int*)eix, flag);
    decode_edges<<<(2 * E_EDGES + 255) / 256, 256, 0, stream>>>(eix, flag, e32, 2 * E_EDGES);
    edge_basis<<<(E_EDGES + 255) / 256, 256, 0, stream>>>(ea, Wp1, bp1, Wp2, bp2, bw, bidx);

    // CSR by dst (once; reused across all 3 layers)
    zero_int<<<(N_NODES + 255) / 256, 256, 0, stream>>>(hist, N_NODES);
    zero_int<<<(N_NODES + 255) / 256, 256, 0, stream>>>(cursor, N_NODES);
    hist_kernel<<<(E_EDGES + 255) / 256, 256, 0, stream>>>(dstv, hist);
    scan_kernel<<<1, 256, 0, stream>>>(hist, rowptr);
    perm_kernel<<<(E_EDGES + 255) / 256, 256, 0, stream>>>(dstv, rowptr, cursor, eperm);

    const float* lin[3]  = {x, h0, h1};
    float*       lout[3] = {h0, h1, out};

    for (int l = 0; l < 3; l++) {
        convA_kernel<<<(MT_TOTAL * 4 * 64 + 255) / 256, 256, 0, stream>>>(
            lin[l], Ah, Al, (l > 0) ? 1 : 0);
        packW_kernel<<<(NB * 4 * 8 * 64 + 255) / 256, 256, 0, stream>>>(
            W[l], Wr[l], Wh, Wl);
        int chunk_id = 0;
        for (long lo = 0; lo < N_NODES; lo += chunk_rows, chunk_id++) {
            long hi = lo + chunk_rows;
            if (hi > N_NODES) hi = N_NODES;
            int mtile_lo = (int)(lo / 16);
            int mtile_hi = (int)(hi / 16);
            int gx = (mtile_hi - mtile_lo + 7) / 8;
            dim3 grid(gx, NB);
            gemm_kernel<<<grid, 256, 0, stream>>>(Ah, Al, Wh, Wl, Z,
                                                  mtile_lo, mtile_hi, (int)lo, (int)hi);
            gather_kernel<<<N_NODES / 4, 256, 0, stream>>>(
                Z, rowptr, eperm, srcv, bw, bidx, b[l], lout[l],
                (int)lo, (int)hi, (chunk_id == 0) ? 1 : 0);
        }
    }
}

// Round 5
// 832.555 us; speedup vs baseline: 5.6321x; 1.1994x over previous
//
#include <hip/hip_runtime.h>
#include <hip/hip_bf16.h>
#include <hip/hip_fp16.h>

#define N_NODES 20000
#define E_EDGES 320000
#define CIN 128
#define HDIM 128
#define EDGE_DIM 16
#define SDIM 3
#define KS 3
#define KK 27           // 3^3 kernel weight matrices
#define NB 28           // 27 spline blocks + 1 root-weight block
#define ZLD (NB * 128)  // Z leading dim = 3584 elements (bf16)
#define S_TAPS 8
#define MLP_HID 6
#define MT_TOTAL (N_NODES / 16)   // 1250 m-tiles of 16 rows

typedef __attribute__((ext_vector_type(8))) short v8s;   // 8 bf16 (4 VGPRs)
typedef __attribute__((ext_vector_type(4))) float v4f;   // MFMA accumulator
typedef unsigned short ush;
typedef unsigned char uch;

static __device__ __forceinline__ short f2bf(float v) {
    unsigned u = __float_as_uint(v);
    unsigned r = (u + 0x7fffu + ((u >> 16) & 1u)) >> 16;   // RTNE
    return (short)r;
}
static __device__ __forceinline__ float bf2f(unsigned s) {
    return __uint_as_float((s & 0xffffu) << 16);
}
static __device__ __forceinline__ unsigned short f2h(float f) {
    __half h = __float2half(f);
    return __half_as_ushort(h);
}
static __device__ __forceinline__ float h2f(unsigned u) {
    __half_raw r; r.x = (unsigned short)u;
    return __half2float(__half(r));
}

// ---------------------------------------------------------------------------
// edge_index dtype detect + decode (int64 vs int32 storage)
// ---------------------------------------------------------------------------
__global__ void detect_kernel(const unsigned int* __restrict__ e, int* __restrict__ flag) {
    __shared__ int s_nz;
    if (threadIdx.x == 0) s_nz = 0;
    __syncthreads();
    unsigned int v = e[threadIdx.x * 2 + 1];
    if (v != 0) atomicAdd(&s_nz, 1);
    __syncthreads();
    if (threadIdx.x == 0) *flag = (s_nz > 0) ? 1 : 0;
}

__global__ void decode_edges(const void* __restrict__ eraw, const int* __restrict__ flag,
                             int* __restrict__ e32, int n) {
    int i = blockIdx.x * blockDim.x + threadIdx.x;
    if (i >= n) return;
    if (*flag) e32[i] = ((const int*)eraw)[i];
    else       e32[i] = (int)(((const long long*)eraw)[i]);
}

// ---------------------------------------------------------------------------
// Edge MLP (16->6 relu ->3 sigmoid) + degree-1 open B-spline basis.
// Emits fp16 weights (wq[E][8]) and byte kernel indices (kq[E][8]).
// ---------------------------------------------------------------------------
__global__ void edge_basis(const float* __restrict__ ea,
                           const float* __restrict__ Wp1, const float* __restrict__ bp1,
                           const float* __restrict__ Wp2, const float* __restrict__ bp2,
                           ush* __restrict__ wq, uch* __restrict__ kq) {
    __shared__ float sW1[EDGE_DIM * MLP_HID];
    __shared__ float sb1[MLP_HID];
    __shared__ float sW2[MLP_HID * SDIM];
    __shared__ float sb2[SDIM];
    int t = threadIdx.x;
    if (t < EDGE_DIM * MLP_HID) sW1[t] = Wp1[t];
    if (t < MLP_HID)            sb1[t] = bp1[t];
    if (t < MLP_HID * SDIM)     sW2[t] = Wp2[t];
    if (t < SDIM)               sb2[t] = bp2[t];
    __syncthreads();
    int e = blockIdx.x * blockDim.x + t;
    if (e >= E_EDGES) return;

    float a[EDGE_DIM];
#pragma unroll
    for (int i = 0; i < EDGE_DIM; i++) a[i] = ea[(long)e * EDGE_DIM + i];

    float hid[MLP_HID];
#pragma unroll
    for (int j = 0; j < MLP_HID; j++) {
        float s = sb1[j];
#pragma unroll
        for (int i = 0; i < EDGE_DIM; i++) s += a[i] * sW1[i * MLP_HID + j];
        hid[j] = fmaxf(s, 0.f);
    }

    float lo[SDIM], fr[SDIM];
#pragma unroll
    for (int d = 0; d < SDIM; d++) {
        float s = sb2[d];
#pragma unroll
        for (int j = 0; j < MLP_HID; j++) s += hid[j] * sW2[j * SDIM + d];
        float u = 1.f / (1.f + expf(-s));
        float v = u * (float)(KS - 1);
        float l = floorf(v);
        l = fminf(fmaxf(l, 0.f), (float)(KS - 2));
        lo[d] = l;
        fr[d] = v - l;
    }

#pragma unroll
    for (int s = 0; s < S_TAPS; s++) {
        float w = 1.f;
        int idx = 0, stride = 1;
#pragma unroll
        for (int d = 0; d < SDIM; d++) {
            int bit = (s >> d) & 1;
            w *= bit ? fr[d] : (1.f - fr[d]);
            idx += ((int)lo[d] + bit) * stride;
            stride *= KS;
        }
        wq[(long)e * S_TAPS + s] = f2h(w);
        kq[(long)e * S_TAPS + s] = (uch)idx;
    }
}

// ---------------------------------------------------------------------------
// CSR build binned by (dst, src-chunk) — built once, reused for 3 layers
// ---------------------------------------------------------------------------
__global__ void zero_int(int* __restrict__ p, int n) {
    int i = blockIdx.x * blockDim.x + threadIdx.x;
    if (i < n) p[i] = 0;
}

__global__ void hist2_kernel(const int* __restrict__ dst, const int* __restrict__ src,
                             int* __restrict__ hist, int nc, int chunk_rows) {
    int e = blockIdx.x * blockDim.x + threadIdx.x;
    if (e >= E_EDGES) return;
    int bin = dst[e] * nc + src[e] / chunk_rows;
    atomicAdd(&hist[bin], 1);
}

__global__ void scan_kernel(const int* __restrict__ hist, int* __restrict__ rowptr, int B) {
    __shared__ int part[256];
    int t = threadIdx.x;
    const int per = (B + 255) / 256;
    int base = t * per;
    int s = 0;
    for (int i = 0; i < per; i++) {
        int idx = base + i;
        if (idx < B) s += hist[idx];
    }
    part[t] = s;
    __syncthreads();
    for (int off = 1; off < 256; off <<= 1) {
        int v = (t >= off) ? part[t - off] : 0;
        __syncthreads();
        part[t] += v;
        __syncthreads();
    }
    int run = (t == 0) ? 0 : part[t - 1];
    for (int i = 0; i < per; i++) {
        int idx = base + i;
        if (idx < B) { rowptr[idx] = run; run += hist[idx]; }
    }
    if (t == 255) rowptr[B] = run;
}

__global__ void perm2_kernel(const int* __restrict__ dst, const int* __restrict__ src,
                             const int* __restrict__ rowptr, int* __restrict__ cursor,
                             int* __restrict__ eperm, int nc, int chunk_rows) {
    int e = blockIdx.x * blockDim.x + threadIdx.x;
    if (e >= E_EDGES) return;
    int bin = dst[e] * nc + src[e] / chunk_rows;
    int pos = rowptr[bin] + atomicAdd(&cursor[bin], 1);
    eperm[pos] = e;
}

// Pack metadata into CSR order: sequential streaming in the gather.
__global__ void pack_csr(const int* __restrict__ eperm, const int* __restrict__ src,
                         const ush* __restrict__ wq, const uch* __restrict__ kq,
                         int* __restrict__ srcp, ush* __restrict__ wp, uch* __restrict__ kp) {
    int j = blockIdx.x * blockDim.x + threadIdx.x;
    if (j >= E_EDGES) return;
    int e = eperm[j];
    srcp[j] = src[e];
    *(uint4*)(wp + (size_t)j * 8) = *(const uint4*)(wq + (size_t)e * 8);
    *(uint2*)(kp + (size_t)j * 8) = *(const uint2*)(kq + (size_t)e * 8);
}

// ---------------------------------------------------------------------------
// Convert activations -> bf16 hi/lo in MFMA A-fragment layout.
// ---------------------------------------------------------------------------
__global__ void convA_kernel(const float* __restrict__ A, short* __restrict__ hi,
                             short* __restrict__ lo, int do_relu) {
    int gid = blockIdx.x * blockDim.x + threadIdx.x;
    if (gid >= MT_TOTAL * 4 * 64) return;
    int lane = gid & 63;
    int ks = (gid >> 6) & 3;
    int mt = gid >> 8;
    int row = mt * 16 + (lane & 15);
    int col = ks * 32 + ((lane >> 4) & 3) * 8;
    const float* p = A + (long)row * CIN + col;
    long off = ((long)(mt * 4 + ks) * 64 + lane) * 8;
#pragma unroll
    for (int j = 0; j < 8; j++) {
        float v = p[j];
        if (do_relu) v = fmaxf(v, 0.f);
        short h = f2bf(v);
        float r = v - bf2f((unsigned short)h);
        hi[off + j] = h;
        lo[off + j] = f2bf(r);
    }
}

// ---------------------------------------------------------------------------
// Pack [W (27 blocks) | Wr] -> bf16 hi/lo in MFMA B-fragment layout.
// ---------------------------------------------------------------------------
__global__ void packW_kernel(const float* __restrict__ W, const float* __restrict__ Wr,
                             short* __restrict__ hi, short* __restrict__ lo) {
    int gid = blockIdx.x * blockDim.x + threadIdx.x;
    if (gid >= NB * 4 * 8 * 64) return;
    int lane = gid & 63;
    int nt = (gid >> 6) & 7;
    int ks = (gid >> 9) & 3;
    int kb = gid >> 11;
    int i0 = ks * 32 + ((lane >> 4) & 3) * 8;
    int o = nt * 16 + (lane & 15);
    const float* src = (kb < KK) ? (W + (long)kb * 16384 + (long)i0 * 128 + o)
                                 : (Wr + (long)i0 * 128 + o);
    long off = ((long)((kb * 4 + ks) * 8 + nt) * 64 + lane) * 8;
#pragma unroll
    for (int j = 0; j < 8; j++) {
        float v = src[(long)j * 128];
        short h = f2bf(v);
        float r = v - bf2f((unsigned short)h);
        hi[off + j] = h;
        lo[off + j] = f2bf(r);
    }
}

// ---------------------------------------------------------------------------
// MFMA GEMM: Z[row-row_lo, kb*128+o] = sum_i A[row,i]*B[kb][i][o]  (bf16 out)
// Split-bf16 3-pass (AhiBhi + AloBhi + AhiBlo) ~= fp32 inputs.
// ---------------------------------------------------------------------------
__global__ __launch_bounds__(256) void gemm_kernel(
    const short* __restrict__ Ah, const short* __restrict__ Al,
    const short* __restrict__ Wh, const short* __restrict__ Wl,
    ush* __restrict__ Z, int mtile_lo, int mtile_hi, int row_lo, int row_hi)
{
    int wave = threadIdx.x >> 6;
    int lane = threadIdx.x & 63;
    int mt0 = mtile_lo + blockIdx.x * 8 + wave * 2;
    if (mt0 >= mtile_hi) return;
    int mt1 = (mt0 + 1 < mtile_hi) ? (mt0 + 1) : mt0;
    int kb = blockIdx.y;

    v4f acc[2][8];
#pragma unroll
    for (int m = 0; m < 2; m++)
#pragma unroll
        for (int n = 0; n < 8; n++) acc[m][n] = (v4f){0.f, 0.f, 0.f, 0.f};

#pragma unroll
    for (int ks = 0; ks < 4; ks++) {
        long a0 = ((long)(mt0 * 4 + ks) * 64 + lane) * 8;
        long a1 = ((long)(mt1 * 4 + ks) * 64 + lane) * 8;
        v8s ah0 = *(const v8s*)(Ah + a0);
        v8s al0 = *(const v8s*)(Al + a0);
        v8s ah1 = *(const v8s*)(Ah + a1);
        v8s al1 = *(const v8s*)(Al + a1);
#pragma unroll
        for (int nt = 0; nt < 8; nt++) {
            long boff = ((long)((kb * 4 + ks) * 8 + nt) * 64 + lane) * 8;
            v8s bh = *(const v8s*)(Wh + boff);
            v8s bl = *(const v8s*)(Wl + boff);
            acc[0][nt] = __builtin_amdgcn_mfma_f32_16x16x32_bf16(ah0, bh, acc[0][nt], 0, 0, 0);
            acc[0][nt] = __builtin_amdgcn_mfma_f32_16x16x32_bf16(al0, bh, acc[0][nt], 0, 0, 0);
            acc[0][nt] = __builtin_amdgcn_mfma_f32_16x16x32_bf16(ah0, bl, acc[0][nt], 0, 0, 0);
            acc[1][nt] = __builtin_amdgcn_mfma_f32_16x16x32_bf16(ah1, bh, acc[1][nt], 0, 0, 0);
            acc[1][nt] = __builtin_amdgcn_mfma_f32_16x16x32_bf16(al1, bh, acc[1][nt], 0, 0, 0);
            acc[1][nt] = __builtin_amdgcn_mfma_f32_16x16x32_bf16(ah1, bl, acc[1][nt], 0, 0, 0);
        }
    }

    // C/D layout: col = lane&15, row-in-tile = (lane>>4)*4 + reg
#pragma unroll
    for (int m = 0; m < 2; m++) {
        int mtg = mt0 + m;
        if (mtg >= mtile_hi) break;
#pragma unroll
        for (int nt = 0; nt < 8; nt++) {
            int col = kb * 128 + nt * 16 + (lane & 15);
#pragma unroll
            for (int r = 0; r < 4; r++) {
                int row = mtg * 16 + ((lane >> 4) & 3) * 4 + r;
                if (row >= row_hi) continue;
                Z[(size_t)(row - row_lo) * ZLD + col] = (ush)f2bf(acc[m][nt][r]);
            }
        }
    }
}

// ---------------------------------------------------------------------------
// Gather v2: one wave per dst node; lane owns 2 channels. Metadata is
// pre-permuted into CSR order and binned by (dst, src-chunk): sequential
// streaming, no skips, no eperm indirection. 8 independent bf16 Z loads
// per edge; unroll 2 -> ~16 outstanding.
// ---------------------------------------------------------------------------
__global__ __launch_bounds__(256) void gather2_kernel(
    const ush* __restrict__ Z, const int* __restrict__ rowptr,
    const int* __restrict__ srcp, const ush* __restrict__ wp,
    const uch* __restrict__ kp, const float* __restrict__ bias,
    float* __restrict__ outp, int lo, int hi, int nc, int cidx, int first)
{
    int wave = threadIdx.x >> 6;
    int lane = threadIdx.x & 63;
    int n = blockIdx.x * 4 + wave;
    int c0 = lane * 2;

    int bin = n * nc + cidx;
    int jb = rowptr[bin], je = rowptr[bin + 1];

    float ax = 0.f, ay = 0.f, bx = 0.f, by = 0.f;
#pragma unroll 2
    for (int j = jb; j < je; j++) {
        int s = srcp[j];
        uint4 wb = *(const uint4*)(wp + (size_t)j * 8);
        uint2 kb = *(const uint2*)(kp + (size_t)j * 8);
        const ush* zb = Z + (size_t)(s - lo) * ZLD + c0;
        ushort2 z;
        float w;
        z = *(const ushort2*)(zb + (kb.x & 0xff) * 128);
        w = h2f(wb.x & 0xffff);  ax += w * bf2f(z.x); ay += w * bf2f(z.y);
        z = *(const ushort2*)(zb + ((kb.x >> 8) & 0xff) * 128);
        w = h2f(wb.x >> 16);     bx += w * bf2f(z.x); by += w * bf2f(z.y);
        z = *(const ushort2*)(zb + ((kb.x >> 16) & 0xff) * 128);
        w = h2f(wb.y & 0xffff);  ax += w * bf2f(z.x); ay += w * bf2f(z.y);
        z = *(const ushort2*)(zb + (kb.x >> 24) * 128);
        w = h2f(wb.y >> 16);     bx += w * bf2f(z.x); by += w * bf2f(z.y);
        z = *(const ushort2*)(zb + (kb.y & 0xff) * 128);
        w = h2f(wb.z & 0xffff);  ax += w * bf2f(z.x); ay += w * bf2f(z.y);
        z = *(const ushort2*)(zb + ((kb.y >> 8) & 0xff) * 128);
        w = h2f(wb.z >> 16);     bx += w * bf2f(z.x); by += w * bf2f(z.y);
        z = *(const ushort2*)(zb + ((kb.y >> 16) & 0xff) * 128);
        w = h2f(wb.w & 0xffff);  ax += w * bf2f(z.x); ay += w * bf2f(z.y);
        z = *(const ushort2*)(zb + (kb.y >> 24) * 128);
        w = h2f(wb.w >> 16);     bx += w * bf2f(z.x); by += w * bf2f(z.y);
    }
    float rx = ax + bx, ry = ay + by;
    if (n >= lo && n < hi) {   // root + bias added by the chunk owning node n
        const ush* zr = Z + (size_t)(n - lo) * ZLD + KK * 128 + c0;
        rx += bf2f(zr[0]) + bias[c0];
        ry += bf2f(zr[1]) + bias[c0 + 1];
    }
    float* op = outp + (size_t)n * HDIM + c0;
    if (!first) { rx += op[0]; ry += op[1]; }
    op[0] = rx; op[1] = ry;
}

// ---------------------------------------------------------------------------
extern "C" void kernel_launch(void* const* d_in, const int* in_sizes, int n_in,
                              void* d_out, int out_size, void* d_ws, size_t ws_size,
                              hipStream_t stream) {
    const float* x   = (const float*)d_in[0];
    const void*  eix = d_in[1];
    const float* ea  = (const float*)d_in[2];
    const float* Wp1 = (const float*)d_in[3];
    const float* bp1 = (const float*)d_in[4];
    const float* Wp2 = (const float*)d_in[5];
    const float* bp2 = (const float*)d_in[6];
    const float* W[3]  = {(const float*)d_in[7],  (const float*)d_in[10], (const float*)d_in[13]};
    const float* Wr[3] = {(const float*)d_in[8],  (const float*)d_in[11], (const float*)d_in[14]};
    const float* b[3]  = {(const float*)d_in[9],  (const float*)d_in[12], (const float*)d_in[15]};
    float* out = (float*)d_out;

    char* ws = (char*)d_ws;
    size_t off = 0;
    auto walloc = [&](size_t bytes) -> void* {
        void* p = ws + off;
        off = (off + bytes + 255) & ~(size_t)255;
        return p;
    };
    int*   flag   = (int*)  walloc(sizeof(int));
    int*   e32    = (int*)  walloc(sizeof(int) * 2 * E_EDGES);
    ush*   wq     = (ush*)  walloc(sizeof(ush) * (size_t)E_EDGES * 8);
    uch*   kq     = (uch*)  walloc((size_t)E_EDGES * 8);
    float* h0     = (float*)walloc(sizeof(float) * (size_t)N_NODES * HDIM);
    float* h1     = (float*)walloc(sizeof(float) * (size_t)N_NODES * HDIM);
    short* Ah     = (short*)walloc(sizeof(short) * (size_t)N_NODES * CIN);
    short* Al     = (short*)walloc(sizeof(short) * (size_t)N_NODES * CIN);
    short* Wh     = (short*)walloc(sizeof(short) * (size_t)NB * 128 * 128);
    short* Wl     = (short*)walloc(sizeof(short) * (size_t)NB * 128 * 128);
    int*   eperm  = (int*)  walloc(sizeof(int) * E_EDGES);
    int*   srcp   = (int*)  walloc(sizeof(int) * E_EDGES);
    ush*   wp     = (ush*)  walloc(sizeof(ush) * (size_t)E_EDGES * 8);
    uch*   kp     = (uch*)  walloc((size_t)E_EDGES * 8);

    // Pick the smallest chunk count nc such that CSR arrays + Z fit.
    int  nc = -1;
    long chunk_rows = 0;
    for (int t = 1; t <= 157; t++) {
        long cr = (((N_NODES + t - 1) / t) + 127) / 128 * 128;
        size_t bins = (size_t)N_NODES * t;
        size_t need = 0;
        auto a = [&](size_t bb) { need += (bb + 255) & ~(size_t)255; };
        a(sizeof(int) * bins);           // hist
        a(sizeof(int) * bins);           // cursor
        a(sizeof(int) * (bins + 1));     // rowptr
        a((size_t)cr * ZLD * sizeof(ush)); // Z
        if (off + need <= ws_size) { nc = t; chunk_rows = cr; break; }
    }
    if (nc < 0) { nc = 157; chunk_rows = 128; }
    size_t bins = (size_t)N_NODES * nc;
    int*   hist   = (int*)walloc(sizeof(int) * bins);
    int*   cursor = (int*)walloc(sizeof(int) * bins);
    int*   rowptr = (int*)walloc(sizeof(int) * (bins + 1));
    ush*   Z      = (ush*)walloc((size_t)chunk_rows * ZLD * sizeof(ush));

    int* srcv = e32;
    int* dstv = e32 + E_EDGES;

    detect_kernel<<<1, 1024, 0, stream>>>((const unsigned int*)eix, flag);
    decode_edges<<<(2 * E_EDGES + 255) / 256, 256, 0, stream>>>(eix, flag, e32, 2 * E_EDGES);
    edge_basis<<<(E_EDGES + 255) / 256, 256, 0, stream>>>(ea, Wp1, bp1, Wp2, bp2, wq, kq);

    // CSR binned by (dst, src-chunk); built once, reused across 3 layers
    zero_int<<<((int)bins + 255) / 256, 256, 0, stream>>>(hist, (int)bins);
    zero_int<<<((int)bins + 255) / 256, 256, 0, stream>>>(cursor, (int)bins);
    hist2_kernel<<<(E_EDGES + 255) / 256, 256, 0, stream>>>(dstv, srcv, hist, nc, (int)chunk_rows);
    scan_kernel<<<1, 256, 0, stream>>>(hist, rowptr, (int)bins);
    perm2_kernel<<<(E_EDGES + 255) / 256, 256, 0, stream>>>(dstv, srcv, rowptr, cursor,
                                                            eperm, nc, (int)chunk_rows);
    pack_csr<<<(E_EDGES + 255) / 256, 256, 0, stream>>>(eperm, srcv, wq, kq, srcp, wp, kp);

    const float* lin[3]  = {x, h0, h1};
    float*       lout[3] = {h0, h1, out};

    for (int l = 0; l < 3; l++) {
        convA_kernel<<<(MT_TOTAL * 4 * 64 + 255) / 256, 256, 0, stream>>>(
            lin[l], Ah, Al, (l > 0) ? 1 : 0);
        packW_kernel<<<(NB * 4 * 8 * 64 + 255) / 256, 256, 0, stream>>>(
            W[l], Wr[l], Wh, Wl);
        for (int c = 0; c < nc; c++) {
            long lo = (long)c * chunk_rows;
            long hi = lo + chunk_rows;
            if (hi > N_NODES) hi = N_NODES;
            if (lo >= N_NODES) break;
            int mtile_lo = (int)(lo / 16);
            int mtile_hi = (int)((hi + 15) / 16);
            int gx = (mtile_hi - mtile_lo + 7) / 8;
            dim3 grid(gx, NB);
            gemm_kernel<<<grid, 256, 0, stream>>>(Ah, Al, Wh, Wl, Z,
                                                  mtile_lo, mtile_hi, (int)lo, (int)hi);
            gather2_kernel<<<N_NODES / 4, 256, 0, stream>>>(
                Z, rowptr, srcp, wp, kp, b[l], lout[l],
                (int)lo, (int)hi, nc, c, (c == 0) ? 1 : 0);
        }
    }
}

// Round 6
// 686.417 us; speedup vs baseline: 6.8311x; 1.2129x over previous
//
#include <hip/hip_runtime.h>
#include <hip/hip_bf16.h>
#include <hip/hip_fp16.h>

#define N_NODES 20000
#define E_EDGES 320000
#define CIN 128
#define HDIM 128
#define EDGE_DIM 16
#define SDIM 3
#define KS 3
#define KK 27           // 3^3 kernel weight matrices
#define NB 28           // 27 spline blocks + 1 root-weight block
#define ZLD (NB * 128)  // Z leading dim = 3584 elements (bf16)
#define S_TAPS 8
#define MLP_HID 6
#define MT_TOTAL (N_NODES / 16)   // 1250 m-tiles of 16 rows

typedef __attribute__((ext_vector_type(8))) short v8s;   // 8 bf16 (4 VGPRs)
typedef __attribute__((ext_vector_type(4))) float v4f;   // MFMA accumulator
typedef unsigned short ush;
typedef unsigned char uch;

static __device__ __forceinline__ short f2bf(float v) {
    unsigned u = __float_as_uint(v);
    unsigned r = (u + 0x7fffu + ((u >> 16) & 1u)) >> 16;   // RTNE
    return (short)r;
}
static __device__ __forceinline__ float bf2f(unsigned s) {
    return __uint_as_float((s & 0xffffu) << 16);
}
static __device__ __forceinline__ unsigned short f2h(float f) {
    __half h = __float2half(f);
    return __half_as_ushort(h);
}
static __device__ __forceinline__ float h2f(unsigned u) {
    __half_raw r; r.x = (unsigned short)u;
    return __half2float(__half(r));
}

// ---------------------------------------------------------------------------
// edge_index dtype detect + decode (int64 vs int32 storage)
// ---------------------------------------------------------------------------
__global__ void detect_kernel(const unsigned int* __restrict__ e, int* __restrict__ flag) {
    __shared__ int s_nz;
    if (threadIdx.x == 0) s_nz = 0;
    __syncthreads();
    unsigned int v = e[threadIdx.x * 2 + 1];
    if (v != 0) atomicAdd(&s_nz, 1);
    __syncthreads();
    if (threadIdx.x == 0) *flag = (s_nz > 0) ? 1 : 0;
}

__global__ void decode_edges(const void* __restrict__ eraw, const int* __restrict__ flag,
                             int* __restrict__ e32, int n) {
    int i = blockIdx.x * blockDim.x + threadIdx.x;
    if (i >= n) return;
    if (*flag) e32[i] = ((const int*)eraw)[i];
    else       e32[i] = (int)(((const long long*)eraw)[i]);
}

// ---------------------------------------------------------------------------
// Edge MLP (16->6 relu ->3 sigmoid) + degree-1 open B-spline basis.
// Emits fp16 weights (wq[E][8]) and byte kernel indices (kq[E][8]).
// ---------------------------------------------------------------------------
__global__ void edge_basis(const float* __restrict__ ea,
                           const float* __restrict__ Wp1, const float* __restrict__ bp1,
                           const float* __restrict__ Wp2, const float* __restrict__ bp2,
                           ush* __restrict__ wq, uch* __restrict__ kq) {
    __shared__ float sW1[EDGE_DIM * MLP_HID];
    __shared__ float sb1[MLP_HID];
    __shared__ float sW2[MLP_HID * SDIM];
    __shared__ float sb2[SDIM];
    int t = threadIdx.x;
    if (t < EDGE_DIM * MLP_HID) sW1[t] = Wp1[t];
    if (t < MLP_HID)            sb1[t] = bp1[t];
    if (t < MLP_HID * SDIM)     sW2[t] = Wp2[t];
    if (t < SDIM)               sb2[t] = bp2[t];
    __syncthreads();
    int e = blockIdx.x * blockDim.x + t;
    if (e >= E_EDGES) return;

    float a[EDGE_DIM];
#pragma unroll
    for (int i = 0; i < EDGE_DIM; i++) a[i] = ea[(long)e * EDGE_DIM + i];

    float hid[MLP_HID];
#pragma unroll
    for (int j = 0; j < MLP_HID; j++) {
        float s = sb1[j];
#pragma unroll
        for (int i = 0; i < EDGE_DIM; i++) s += a[i] * sW1[i * MLP_HID + j];
        hid[j] = fmaxf(s, 0.f);
    }

    float lo[SDIM], fr[SDIM];
#pragma unroll
    for (int d = 0; d < SDIM; d++) {
        float s = sb2[d];
#pragma unroll
        for (int j = 0; j < MLP_HID; j++) s += hid[j] * sW2[j * SDIM + d];
        float u = 1.f / (1.f + expf(-s));
        float v = u * (float)(KS - 1);
        float l = floorf(v);
        l = fminf(fmaxf(l, 0.f), (float)(KS - 2));
        lo[d] = l;
        fr[d] = v - l;
    }

#pragma unroll
    for (int s = 0; s < S_TAPS; s++) {
        float w = 1.f;
        int idx = 0, stride = 1;
#pragma unroll
        for (int d = 0; d < SDIM; d++) {
            int bit = (s >> d) & 1;
            w *= bit ? fr[d] : (1.f - fr[d]);
            idx += ((int)lo[d] + bit) * stride;
            stride *= KS;
        }
        wq[(long)e * S_TAPS + s] = f2h(w);
        kq[(long)e * S_TAPS + s] = (uch)idx;
    }
}

// ---------------------------------------------------------------------------
// CSR build binned by (dst, src-chunk) — built once, reused for 3 layers
// ---------------------------------------------------------------------------
__global__ void zero_int(int* __restrict__ p, int n) {
    int i = blockIdx.x * blockDim.x + threadIdx.x;
    if (i < n) p[i] = 0;
}

__global__ void hist2_kernel(const int* __restrict__ dst, const int* __restrict__ src,
                             int* __restrict__ hist, int nc, int chunk_rows) {
    int e = blockIdx.x * blockDim.x + threadIdx.x;
    if (e >= E_EDGES) return;
    int bin = dst[e] * nc + src[e] / chunk_rows;
    atomicAdd(&hist[bin], 1);
}

__global__ void scan_kernel(const int* __restrict__ hist, int* __restrict__ rowptr, int B) {
    __shared__ int part[256];
    int t = threadIdx.x;
    const int per = (B + 255) / 256;
    int base = t * per;
    int s = 0;
    for (int i = 0; i < per; i++) {
        int idx = base + i;
        if (idx < B) s += hist[idx];
    }
    part[t] = s;
    __syncthreads();
    for (int off = 1; off < 256; off <<= 1) {
        int v = (t >= off) ? part[t - off] : 0;
        __syncthreads();
        part[t] += v;
        __syncthreads();
    }
    int run = (t == 0) ? 0 : part[t - 1];
    for (int i = 0; i < per; i++) {
        int idx = base + i;
        if (idx < B) { rowptr[idx] = run; run += hist[idx]; }
    }
    if (t == 255) rowptr[B] = run;
}

__global__ void perm2_kernel(const int* __restrict__ dst, const int* __restrict__ src,
                             const int* __restrict__ rowptr, int* __restrict__ cursor,
                             int* __restrict__ eperm, int nc, int chunk_rows) {
    int e = blockIdx.x * blockDim.x + threadIdx.x;
    if (e >= E_EDGES) return;
    int bin = dst[e] * nc + src[e] / chunk_rows;
    int pos = rowptr[bin] + atomicAdd(&cursor[bin], 1);
    eperm[pos] = e;
}

// Pack metadata into CSR order: sequential streaming in the gather.
__global__ void pack_csr(const int* __restrict__ eperm, const int* __restrict__ src,
                         const ush* __restrict__ wq, const uch* __restrict__ kq,
                         int* __restrict__ srcp, ush* __restrict__ wp, uch* __restrict__ kp) {
    int j = blockIdx.x * blockDim.x + threadIdx.x;
    if (j >= E_EDGES) return;
    int e = eperm[j];
    srcp[j] = src[e];
    *(uint4*)(wp + (size_t)j * 8) = *(const uint4*)(wq + (size_t)e * 8);
    *(uint2*)(kp + (size_t)j * 8) = *(const uint2*)(kq + (size_t)e * 8);
}

// ---------------------------------------------------------------------------
// Convert activations -> bf16 hi/lo in MFMA A-fragment layout.
// ---------------------------------------------------------------------------
__global__ void convA_kernel(const float* __restrict__ A, short* __restrict__ hi,
                             short* __restrict__ lo, int do_relu) {
    int gid = blockIdx.x * blockDim.x + threadIdx.x;
    if (gid >= MT_TOTAL * 4 * 64) return;
    int lane = gid & 63;
    int ks = (gid >> 6) & 3;
    int mt = gid >> 8;
    int row = mt * 16 + (lane & 15);
    int col = ks * 32 + ((lane >> 4) & 3) * 8;
    const float* p = A + (long)row * CIN + col;
    long off = ((long)(mt * 4 + ks) * 64 + lane) * 8;
#pragma unroll
    for (int j = 0; j < 8; j++) {
        float v = p[j];
        if (do_relu) v = fmaxf(v, 0.f);
        short h = f2bf(v);
        float r = v - bf2f((unsigned short)h);
        hi[off + j] = h;
        lo[off + j] = f2bf(r);
    }
}

// ---------------------------------------------------------------------------
// Pack [W (27 blocks) | Wr] -> bf16 in MFMA B-fragment layout (hi only).
// ---------------------------------------------------------------------------
__global__ void packW_kernel(const float* __restrict__ W, const float* __restrict__ Wr,
                             short* __restrict__ hi) {
    int gid = blockIdx.x * blockDim.x + threadIdx.x;
    if (gid >= NB * 4 * 8 * 64) return;
    int lane = gid & 63;
    int nt = (gid >> 6) & 7;
    int ks = (gid >> 9) & 3;
    int kb = gid >> 11;
    int i0 = ks * 32 + ((lane >> 4) & 3) * 8;
    int o = nt * 16 + (lane & 15);
    const float* src = (kb < KK) ? (W + (long)kb * 16384 + (long)i0 * 128 + o)
                                 : (Wr + (long)i0 * 128 + o);
    long off = ((long)((kb * 4 + ks) * 8 + nt) * 64 + lane) * 8;
#pragma unroll
    for (int j = 0; j < 8; j++) {
        float v = src[(long)j * 128];
        hi[off + j] = f2bf(v);
    }
}

// ---------------------------------------------------------------------------
// MFMA GEMM: Z[row-row_lo, kb*128+o] = sum_i A[row,i]*B[kb][i][o]  (bf16 out)
// Split-bf16 2-pass on A (AhiB + AloB); W plain bf16 — its rounding error is
// the same order as the bf16 Z storage quantization.
// grid = (kb=NB fast, m-group): consecutive blocks share the same 131 KB
// A-slice (L2-resident) instead of streaming all 20.5 MB of A per kb.
// ---------------------------------------------------------------------------
__global__ __launch_bounds__(256) void gemm_kernel(
    const short* __restrict__ Ah, const short* __restrict__ Al,
    const short* __restrict__ Wh,
    ush* __restrict__ Z, int mtile_lo, int mtile_hi, int row_lo, int row_hi)
{
    int wave = threadIdx.x >> 6;
    int lane = threadIdx.x & 63;
    int kb = blockIdx.x;                               // fast-varying -> A locality
    int mt0 = mtile_lo + blockIdx.y * 8 + wave * 2;
    if (mt0 >= mtile_hi) return;
    int mt1 = (mt0 + 1 < mtile_hi) ? (mt0 + 1) : mt0;

    v4f acc[2][8];
#pragma unroll
    for (int m = 0; m < 2; m++)
#pragma unroll
        for (int n = 0; n < 8; n++) acc[m][n] = (v4f){0.f, 0.f, 0.f, 0.f};

#pragma unroll
    for (int ks = 0; ks < 4; ks++) {
        long a0 = ((long)(mt0 * 4 + ks) * 64 + lane) * 8;
        long a1 = ((long)(mt1 * 4 + ks) * 64 + lane) * 8;
        v8s ah0 = *(const v8s*)(Ah + a0);
        v8s al0 = *(const v8s*)(Al + a0);
        v8s ah1 = *(const v8s*)(Ah + a1);
        v8s al1 = *(const v8s*)(Al + a1);
#pragma unroll
        for (int nt = 0; nt < 8; nt++) {
            long boff = ((long)((kb * 4 + ks) * 8 + nt) * 64 + lane) * 8;
            v8s bh = *(const v8s*)(Wh + boff);
            acc[0][nt] = __builtin_amdgcn_mfma_f32_16x16x32_bf16(ah0, bh, acc[0][nt], 0, 0, 0);
            acc[0][nt] = __builtin_amdgcn_mfma_f32_16x16x32_bf16(al0, bh, acc[0][nt], 0, 0, 0);
            acc[1][nt] = __builtin_amdgcn_mfma_f32_16x16x32_bf16(ah1, bh, acc[1][nt], 0, 0, 0);
            acc[1][nt] = __builtin_amdgcn_mfma_f32_16x16x32_bf16(al1, bh, acc[1][nt], 0, 0, 0);
        }
    }

    // C/D layout: col = lane&15, row-in-tile = (lane>>4)*4 + reg
#pragma unroll
    for (int m = 0; m < 2; m++) {
        int mtg = mt0 + m;
        if (mtg >= mtile_hi) break;
#pragma unroll
        for (int nt = 0; nt < 8; nt++) {
            int col = kb * 128 + nt * 16 + (lane & 15);
#pragma unroll
            for (int r = 0; r < 4; r++) {
                int row = mtg * 16 + ((lane >> 4) & 3) * 4 + r;
                if (row >= row_hi) continue;
                Z[(size_t)(row - row_lo) * ZLD + col] = (ush)f2bf(acc[m][nt][r]);
            }
        }
    }
}

// ---------------------------------------------------------------------------
// Gather: one wave per dst node; lane owns 2 channels. Metadata pre-permuted
// into CSR order, binned by (dst, src-chunk): sequential streaming.
// ---------------------------------------------------------------------------
__global__ __launch_bounds__(256) void gather2_kernel(
    const ush* __restrict__ Z, const int* __restrict__ rowptr,
    const int* __restrict__ srcp, const ush* __restrict__ wp,
    const uch* __restrict__ kp, const float* __restrict__ bias,
    float* __restrict__ outp, int lo, int hi, int nc, int cidx, int first)
{
    int wave = threadIdx.x >> 6;
    int lane = threadIdx.x & 63;
    int n = blockIdx.x * 4 + wave;
    int c0 = lane * 2;

    int bin = n * nc + cidx;
    int jb = rowptr[bin], je = rowptr[bin + 1];

    float ax = 0.f, ay = 0.f, bx = 0.f, by = 0.f;
#pragma unroll 2
    for (int j = jb; j < je; j++) {
        int s = srcp[j];
        uint4 wb = *(const uint4*)(wp + (size_t)j * 8);
        uint2 kb = *(const uint2*)(kp + (size_t)j * 8);
        const ush* zb = Z + (size_t)(s - lo) * ZLD + c0;
        ushort2 z;
        float w;
        z = *(const ushort2*)(zb + (kb.x & 0xff) * 128);
        w = h2f(wb.x & 0xffff);  ax += w * bf2f(z.x); ay += w * bf2f(z.y);
        z = *(const ushort2*)(zb + ((kb.x >> 8) & 0xff) * 128);
        w = h2f(wb.x >> 16);     bx += w * bf2f(z.x); by += w * bf2f(z.y);
        z = *(const ushort2*)(zb + ((kb.x >> 16) & 0xff) * 128);
        w = h2f(wb.y & 0xffff);  ax += w * bf2f(z.x); ay += w * bf2f(z.y);
        z = *(const ushort2*)(zb + (kb.x >> 24) * 128);
        w = h2f(wb.y >> 16);     bx += w * bf2f(z.x); by += w * bf2f(z.y);
        z = *(const ushort2*)(zb + (kb.y & 0xff) * 128);
        w = h2f(wb.z & 0xffff);  ax += w * bf2f(z.x); ay += w * bf2f(z.y);
        z = *(const ushort2*)(zb + ((kb.y >> 8) & 0xff) * 128);
        w = h2f(wb.z >> 16);     bx += w * bf2f(z.x); by += w * bf2f(z.y);
        z = *(const ushort2*)(zb + ((kb.y >> 16) & 0xff) * 128);
        w = h2f(wb.w & 0xffff);  ax += w * bf2f(z.x); ay += w * bf2f(z.y);
        z = *(const ushort2*)(zb + (kb.y >> 24) * 128);
        w = h2f(wb.w >> 16);     bx += w * bf2f(z.x); by += w * bf2f(z.y);
    }
    float rx = ax + bx, ry = ay + by;
    if (n >= lo && n < hi) {   // root + bias added by the chunk owning node n
        const ush* zr = Z + (size_t)(n - lo) * ZLD + KK * 128 + c0;
        rx += bf2f(zr[0]) + bias[c0];
        ry += bf2f(zr[1]) + bias[c0 + 1];
    }
    float* op = outp + (size_t)n * HDIM + c0;
    if (!first) { rx += op[0]; ry += op[1]; }
    op[0] = rx; op[1] = ry;
}

// ---------------------------------------------------------------------------
extern "C" void kernel_launch(void* const* d_in, const int* in_sizes, int n_in,
                              void* d_out, int out_size, void* d_ws, size_t ws_size,
                              hipStream_t stream) {
    const float* x   = (const float*)d_in[0];
    const void*  eix = d_in[1];
    const float* ea  = (const float*)d_in[2];
    const float* Wp1 = (const float*)d_in[3];
    const float* bp1 = (const float*)d_in[4];
    const float* Wp2 = (const float*)d_in[5];
    const float* bp2 = (const float*)d_in[6];
    const float* W[3]  = {(const float*)d_in[7],  (const float*)d_in[10], (const float*)d_in[13]};
    const float* Wr[3] = {(const float*)d_in[8],  (const float*)d_in[11], (const float*)d_in[14]};
    const float* b[3]  = {(const float*)d_in[9],  (const float*)d_in[12], (const float*)d_in[15]};
    float* out = (float*)d_out;

    char* ws = (char*)d_ws;
    size_t off = 0;
    auto walloc = [&](size_t bytes) -> void* {
        void* p = ws + off;
        off = (off + bytes + 255) & ~(size_t)255;
        return p;
    };
    int*   flag   = (int*)  walloc(sizeof(int));
    int*   e32    = (int*)  walloc(sizeof(int) * 2 * E_EDGES);
    ush*   wq     = (ush*)  walloc(sizeof(ush) * (size_t)E_EDGES * 8);
    uch*   kq     = (uch*)  walloc((size_t)E_EDGES * 8);
    float* h0     = (float*)walloc(sizeof(float) * (size_t)N_NODES * HDIM);
    float* h1     = (float*)walloc(sizeof(float) * (size_t)N_NODES * HDIM);
    short* Ah     = (short*)walloc(sizeof(short) * (size_t)N_NODES * CIN);
    short* Al     = (short*)walloc(sizeof(short) * (size_t)N_NODES * CIN);
    short* Wh     = (short*)walloc(sizeof(short) * (size_t)NB * 128 * 128);
    int*   eperm  = (int*)  walloc(sizeof(int) * E_EDGES);
    int*   srcp   = (int*)  walloc(sizeof(int) * E_EDGES);
    ush*   wp     = (ush*)  walloc(sizeof(ush) * (size_t)E_EDGES * 8);
    uch*   kp     = (uch*)  walloc((size_t)E_EDGES * 8);

    // Pick the smallest chunk count nc such that CSR arrays + Z fit.
    int  nc = -1;
    long chunk_rows = 0;
    for (int t = 1; t <= 157; t++) {
        long cr = (((N_NODES + t - 1) / t) + 127) / 128 * 128;
        size_t bins = (size_t)N_NODES * t;
        size_t need = 0;
        auto a = [&](size_t bb) { need += (bb + 255) & ~(size_t)255; };
        a(sizeof(int) * bins);             // hist
        a(sizeof(int) * bins);             // cursor
        a(sizeof(int) * (bins + 1));       // rowptr
        a((size_t)cr * ZLD * sizeof(ush)); // Z
        if (off + need <= ws_size) { nc = t; chunk_rows = cr; break; }
    }
    if (nc < 0) { nc = 157; chunk_rows = 128; }
    size_t bins = (size_t)N_NODES * nc;
    int*   hist   = (int*)walloc(sizeof(int) * bins);
    int*   cursor = (int*)walloc(sizeof(int) * bins);
    int*   rowptr = (int*)walloc(sizeof(int) * (bins + 1));
    ush*   Z      = (ush*)walloc((size_t)chunk_rows * ZLD * sizeof(ush));

    int* srcv = e32;
    int* dstv = e32 + E_EDGES;

    detect_kernel<<<1, 1024, 0, stream>>>((const unsigned int*)eix, flag);
    decode_edges<<<(2 * E_EDGES + 255) / 256, 256, 0, stream>>>(eix, flag, e32, 2 * E_EDGES);
    edge_basis<<<(E_EDGES + 255) / 256, 256, 0, stream>>>(ea, Wp1, bp1, Wp2, bp2, wq, kq);

    // CSR binned by (dst, src-chunk); built once, reused across 3 layers
    zero_int<<<((int)bins + 255) / 256, 256, 0, stream>>>(hist, (int)bins);
    zero_int<<<((int)bins + 255) / 256, 256, 0, stream>>>(cursor, (int)bins);
    hist2_kernel<<<(E_EDGES + 255) / 256, 256, 0, stream>>>(dstv, srcv, hist, nc, (int)chunk_rows);
    scan_kernel<<<1, 256, 0, stream>>>(hist, rowptr, (int)bins);
    perm2_kernel<<<(E_EDGES + 255) / 256, 256, 0, stream>>>(dstv, srcv, rowptr, cursor,
                                                            eperm, nc, (int)chunk_rows);
    pack_csr<<<(E_EDGES + 255) / 256, 256, 0, stream>>>(eperm, srcv, wq, kq, srcp, wp, kp);

    const float* lin[3]  = {x, h0, h1};
    float*       lout[3] = {h0, h1, out};

    for (int l = 0; l < 3; l++) {
        convA_kernel<<<(MT_TOTAL * 4 * 64 + 255) / 256, 256, 0, stream>>>(
            lin[l], Ah, Al, (l > 0) ? 1 : 0);
        packW_kernel<<<(NB * 4 * 8 * 64 + 255) / 256, 256, 0, stream>>>(
            W[l], Wr[l], Wh);
        for (int c = 0; c < nc; c++) {
            long lo = (long)c * chunk_rows;
            long hi = lo + chunk_rows;
            if (hi > N_NODES) hi = N_NODES;
            if (lo >= N_NODES) break;
            int mtile_lo = (int)(lo / 16);
            int mtile_hi = (int)((hi + 15) / 16);
            int gy = (mtile_hi - mtile_lo + 7) / 8;
            dim3 grid(NB, gy);
            gemm_kernel<<<grid, 256, 0, stream>>>(Ah, Al, Wh, Z,
                                                  mtile_lo, mtile_hi, (int)lo, (int)hi);
            gather2_kernel<<<N_NODES / 4, 256, 0, stream>>>(
                Z, rowptr, srcp, wp, kp, b[l], lout[l],
                (int)lo, (int)hi, nc, c, (c == 0) ? 1 : 0);
        }
    }
}